// Round 2
// baseline (692.507 us; speedup 1.0000x reference)
//
#include <hip/hip_runtime.h>

#define N_NODES    1000000
#define N_EDGES    32000000
#define NUM_GRAPHS 1024

typedef int          vint4  __attribute__((ext_vector_type(4)));
typedef unsigned int uint32;
typedef unsigned int vuint4 __attribute__((ext_vector_type(4)));

#define BUCKET_SHIFT 12
#define BUCKET_NODES (1 << BUCKET_SHIFT)          // 4096 nodes/bucket
#define NBUCKETS     245                          // ceil(1e6 / 4096)

// ---- Tier 1: slab + LDS-staged line flush ----------------------------------
#define T1_NCHUNK   512
#define T1_BLOCK    512
#define T1_EDGES_PER_CHUNK (N_EDGES / T1_NCHUNK)  // 62500
#define T1_QUADS    (T1_EDGES_PER_CHUNK / 4)      // 15625
#define T1_ROUNDS   ((T1_QUADS + T1_BLOCK - 1) / T1_BLOCK)  // 31
#define SCAP        64                            // LDS staging slots per bucket (4 lines)
#define SLAB_CAP    368                           // per-cell slots: mean 256 + 7 sigma, %16==0

// reduce v3: split each bucket across RSPLIT WGs (cells) x SRC_SPLIT WGs (src range).
// src-half is keyed to blockIdx&1 so it lands on a fixed XCD parity -> each XCD's
// L2 only needs a 2 MB slice of x -> gathers become L2 hits instead of L3 fills.
#define RSPLIT        4
#define CELLS_PER_WG  (T1_NCHUNK / RSPLIT)        // 128
#define SRC_SPLIT     2
#define HALF_NODES    (N_NODES / SRC_SPLIT)       // 500000

// ---- Tier 2 (known-good round-4 path) ---------------------------------------
#define T2_CAP      136192
#define T2_NCHUNK   512
#define T2_EPC      (N_EDGES / T2_NCHUNK)

// ============================================================================
// Tier 1 scatter v2: no histogram pass. Rounds of 2048 edges (4/thread):
//   phase A: claim staging slot via LDS atomic; index < SCAP -> stage in LDS,
//            else (≈never) direct store to slab tail.
//   phase B: flush complete 16-entry (64B) lines coalesced, compact remainder.
// NT hints on edge loads + slab stores: scatter is stream-only, keep L2 clean
// for the following reduce's x[] gathers.
// ============================================================================
__global__ __launch_bounds__(T1_BLOCK)
void slab_scatter(const int* __restrict__ src,
                  const int* __restrict__ dst,
                  uint32* __restrict__ slab,
                  uint32* __restrict__ fcnt_g,
                  uint32* __restrict__ ecnt_g) {
    __shared__ uint32 stage[NBUCKETS][SCAP];
    __shared__ uint32 rpos[NBUCKETS];     // claims this round
    __shared__ uint32 ecnt[NBUCKETS];     // tail (overflow) count
    __shared__ uint32 flushed[NBUCKETS];  // front entries already in slab
    __shared__ uint32 carry[NBUCKETS];    // staged entries carried across rounds

    const int tid = threadIdx.x;
    const int w   = blockIdx.x;
    const vint4* d4 = (const vint4*)(dst + (size_t)w * T1_EDGES_PER_CHUNK);
    const vint4* s4 = (const vint4*)(src + (size_t)w * T1_EDGES_PER_CHUNK);

    for (int b = tid; b < NBUCKETS; b += T1_BLOCK) {
        rpos[b] = 0; ecnt[b] = 0; flushed[b] = 0; carry[b] = 0;
    }
    __syncthreads();

    const int grp    = tid >> 4;    // 32 groups of 16 lanes
    const int lane16 = tid & 15;

    for (int r = 0; r < T1_ROUNDS; ++r) {
        int q = r * T1_BLOCK + tid;
        if (q < T1_QUADS) {
            vint4 d = __builtin_nontemporal_load(&d4[q]);
            vint4 s = __builtin_nontemporal_load(&s4[q]);
            #pragma unroll
            for (int k = 0; k < 4; ++k) {
                uint32 dd = (uint32)(k == 0 ? d.x : k == 1 ? d.y : k == 2 ? d.z : d.w);
                uint32 ss = (uint32)(k == 0 ? s.x : k == 1 ? s.y : k == 2 ? s.z : s.w);
                uint32 b  = dd >> BUCKET_SHIFT;
                uint32 v  = ((dd & (BUCKET_NODES - 1)) << 20) | ss;
                uint32 c  = carry[b] + atomicAdd(&rpos[b], 1u);
                if (c < SCAP) {
                    stage[b][c] = v;
                } else {
                    uint32 e = atomicAdd(&ecnt[b], 1u);
                    __builtin_nontemporal_store(v,
                        &slab[((size_t)b * T1_NCHUNK + w) * SLAB_CAP + (SLAB_CAP - 1 - e)]);
                }
            }
        }
        __syncthreads();
        // phase B: flush complete lines; 16-lane group owns buckets grp, grp+32, ...
        for (int b = grp; b < NBUCKETS; b += 32) {
            uint32 tot = carry[b] + rpos[b];
            if (tot > SCAP) tot = SCAP;
            uint32 lines = tot >> 4;
            uint32 rem   = tot & 15u;
            uint32 fl    = flushed[b];
            uint32* dp = slab + ((size_t)b * T1_NCHUNK + w) * SLAB_CAP + fl;
            for (uint32 l = 0; l < lines; ++l)
                __builtin_nontemporal_store(stage[b][l * 16 + lane16],
                                            &dp[l * 16 + lane16]);   // 64B coalesced
            if (lines) {
                uint32 mv = 0;
                if (lane16 < rem) mv = stage[b][lines * 16 + lane16];
                if (lane16 < rem) stage[b][lane16] = mv;             // compact remainder
            }
            if (lane16 == 0) {
                flushed[b] = fl + lines * 16;
                carry[b]   = rem;
                rpos[b]    = 0;
            }
        }
        __syncthreads();
    }
    // epilogue: flush partial remainder, publish per-cell counts
    for (int b = grp; b < NBUCKETS; b += 32) {
        uint32 rem = carry[b];
        uint32 fl  = flushed[b];
        uint32* dp = slab + ((size_t)b * T1_NCHUNK + w) * SLAB_CAP + fl;
        if (lane16 < rem) __builtin_nontemporal_store(stage[b][lane16], &dp[lane16]);
        if (lane16 == 0) {
            fcnt_g[(size_t)b * T1_NCHUNK + w] = fl + rem;
            ecnt_g[(size_t)b * T1_NCHUNK + w] = ecnt[b];
        }
    }
}

// ============================================================================
// Tier 1 reduce v3: grid = NBUCKETS * RSPLIT * SRC_SPLIT.
//   blockIdx&1   = src half   (XCD-parity affine -> 2 MB x slice per L2)
//   rest = blockIdx>>1 ; b = rest / RSPLIT ; part = rest % RSPLIT (cell range)
// Each WG scans its 128 cells' records but only gathers/accumulates edges whose
// src falls in its half. Slab read doubles (HBM, cheap); x gathers become L2
// hits (the whole point).
// ============================================================================
__global__ __launch_bounds__(1024)
void slab_reduce2(const uint32* __restrict__ slab,
                  const uint32* __restrict__ fcnt_g,
                  const uint32* __restrict__ ecnt_g,
                  const float* __restrict__ x,
                  float* __restrict__ agg) {
    __shared__ float  acc[BUCKET_NODES];
    __shared__ uint32 fc_s[CELLS_PER_WG];
    __shared__ uint32 ec_s[CELLS_PER_WG];

    const int half = blockIdx.x & 1;
    const int rest = blockIdx.x >> 1;
    const int b    = rest / RSPLIT;
    const int part = rest % RSPLIT;
    const int tid  = threadIdx.x;

    const uint32 lo = (uint32)half * HALF_NODES;
    const uint32 hi = lo + HALF_NODES;

    for (int n = tid; n < BUCKET_NODES; n += 1024) acc[n] = 0.0f;
    if (tid < CELLS_PER_WG) {
        size_t cell = (size_t)b * T1_NCHUNK + (size_t)part * CELLS_PER_WG + tid;
        fc_s[tid] = fcnt_g[cell];
        ec_s[tid] = ecnt_g[cell];
    }
    __syncthreads();

    const int wv = tid >> 6, lane = tid & 63;
    for (int c = wv; c < CELLS_PER_WG; c += 16) {          // 8 cells per wave
        const int w = part * CELLS_PER_WG + c;
        const size_t cell = (size_t)b * T1_NCHUNK + w;
        const uint32 fc = fc_s[c];
        const uint32 ec = ec_s[c];
        const uint32* base = slab + cell * SLAB_CAP;       // 16B aligned
        const vuint4* b4 = (const vuint4*)base;
        const uint32 nq = fc >> 2;
        for (uint32 i = lane; i < nq; i += 64) {
            vuint4 v = __builtin_nontemporal_load(&b4[i]);
            uint32 s0 = v.x & 0xFFFFFu, s1 = v.y & 0xFFFFFu;
            uint32 s2 = v.z & 0xFFFFFu, s3 = v.w & 0xFFFFFu;
            if (s0 >= lo && s0 < hi) atomicAdd(&acc[v.x >> 20], x[s0]);
            if (s1 >= lo && s1 < hi) atomicAdd(&acc[v.y >> 20], x[s1]);
            if (s2 >= lo && s2 < hi) atomicAdd(&acc[v.z >> 20], x[s2]);
            if (s3 >= lo && s3 < hi) atomicAdd(&acc[v.w >> 20], x[s3]);
        }
        for (uint32 i = nq * 4 + lane; i < fc; i += 64) {
            uint32 v = __builtin_nontemporal_load(&base[i]);
            uint32 s = v & 0xFFFFFu;
            if (s >= lo && s < hi) atomicAdd(&acc[v >> 20], x[s]);
        }
        for (uint32 i = lane; i < ec; i += 64) {
            uint32 v = base[SLAB_CAP - 1 - i];
            uint32 s = v & 0xFFFFFu;
            if (s >= lo && s < hi) atomicAdd(&acc[v >> 20], x[s]);
        }
    }
    __syncthreads();

    // coalesced device-scope merge of this WG's partial sums
    const int node0 = b << BUCKET_SHIFT;
    for (int n = tid; n < BUCKET_NODES; n += 1024) {
        float v = acc[n];
        if (v != 0.0f) atomicAdd(&agg[node0 + n], v);
    }
}

// ============================================================================
// Tier 1 reduce (v1, kept as fallback tier): one WG per bucket, fused pool.
// ============================================================================
__global__ __launch_bounds__(1024)
void slab_reduce(const uint32* __restrict__ slab,
                 const uint32* __restrict__ fcnt_g,
                 const uint32* __restrict__ ecnt_g,
                 const float* __restrict__ x,
                 const int* __restrict__ batch,
                 float* __restrict__ sums,
                 float* __restrict__ counts) {
    __shared__ float acc[BUCKET_NODES];
    const int b = blockIdx.x;
    const int tid = threadIdx.x;
    for (int n = tid; n < BUCKET_NODES; n += 1024) acc[n] = 0.0f;
    __syncthreads();

    const int wv = tid >> 6, lane = tid & 63;
    for (int w = wv; w < T1_NCHUNK; w += 16) {
        size_t cell = (size_t)b * T1_NCHUNK + w;
        uint32 fc = fcnt_g[cell];
        uint32 ec = ecnt_g[cell];
        const uint32* base = slab + cell * SLAB_CAP;     // 16B aligned (SLAB_CAP%4==0)
        const vuint4* b4 = (const vuint4*)base;
        uint32 nq = fc >> 2;
        for (uint32 i = lane; i < nq; i += 64) {
            vuint4 v = b4[i];
            atomicAdd(&acc[v.x >> 20], x[v.x & 0xFFFFFu]);
            atomicAdd(&acc[v.y >> 20], x[v.y & 0xFFFFFu]);
            atomicAdd(&acc[v.z >> 20], x[v.z & 0xFFFFFu]);
            atomicAdd(&acc[v.w >> 20], x[v.w & 0xFFFFFu]);
        }
        for (uint32 i = nq * 4 + lane; i < fc; i += 64) {
            uint32 v = base[i];
            atomicAdd(&acc[v >> 20], x[v & 0xFFFFFu]);
        }
        for (uint32 i = lane; i < ec; i += 64) {
            uint32 v = base[SLAB_CAP - 1 - i];
            atomicAdd(&acc[v >> 20], x[v & 0xFFFFFu]);
        }
    }
    __syncthreads();

    const int node0 = b << BUCKET_SHIFT;
    for (int n = tid; n < BUCKET_NODES; n += 1024) {
        int i = node0 + n;
        float h = 0.0f;
        int g = -1;
        if (i < N_NODES) {
            h = fmaxf(acc[n], 0.0f);
            g = batch[i];
        }
        int g0 = __shfl(g, 0);
        if (__all(g == g0)) {
            #pragma unroll
            for (int off = 32; off > 0; off >>= 1)
                h += __shfl_down(h, off);
            if ((tid & 63) == 0 && g0 >= 0) {
                atomicAdd(&sums[g0], h);
                atomicAdd(&counts[g0], 64.0f);
            }
        } else if (g >= 0) {
            atomicAdd(&sums[g], h);
            atomicAdd(&counts[g], 1.0f);
        }
    }
}

// Stage 3: out[g] = (sums[g] / max(counts[g],1)) * W + b
__global__ void finalize_kernel(const float* __restrict__ sums,
                                const float* __restrict__ counts,
                                const float* __restrict__ W,
                                const float* __restrict__ b,
                                float* __restrict__ out) {
    int g = blockIdx.x * blockDim.x + threadIdx.x;
    if (g < NUM_GRAPHS) {
        float pooled = sums[g] / fmaxf(counts[g], 1.0f);
        out[g] = pooled * W[0] + b[0];
    }
}

// ============================================================================
// Tier 2: round-4 known-good path (atomic block reservation + random stores)
// ============================================================================
__global__ __launch_bounds__(1024)
void bucket_scatter(const int* __restrict__ src,
                    const int* __restrict__ dst,
                    uint32* __restrict__ sorted,
                    uint32* __restrict__ gpos) {
    __shared__ uint32 hist[NBUCKETS];
    __shared__ uint32 pos[NBUCKETS];
    const int tid = threadIdx.x;
    const size_t base = (size_t)blockIdx.x * T2_EPC;
    for (int b = tid; b < NBUCKETS; b += 1024) hist[b] = 0;
    __syncthreads();
    const vint4* d4 = (const vint4*)(dst + base);
    const vint4* s4 = (const vint4*)(src + base);
    const int nvec = T2_EPC / 4;
    for (int i = tid; i < nvec; i += 1024) {
        vint4 d = d4[i];
        atomicAdd(&hist[(uint32)d.x >> BUCKET_SHIFT], 1u);
        atomicAdd(&hist[(uint32)d.y >> BUCKET_SHIFT], 1u);
        atomicAdd(&hist[(uint32)d.z >> BUCKET_SHIFT], 1u);
        atomicAdd(&hist[(uint32)d.w >> BUCKET_SHIFT], 1u);
    }
    __syncthreads();
    for (int b = tid; b < NBUCKETS; b += 1024)
        pos[b] = atomicAdd(&gpos[b], hist[b]);
    __syncthreads();
    for (int i = tid; i < nvec; i += 1024) {
        vint4 d = d4[i];
        vint4 s = s4[i];
        #pragma unroll
        for (int k = 0; k < 4; ++k) {
            uint32 dd = (uint32)(k == 0 ? d.x : k == 1 ? d.y : k == 2 ? d.z : d.w);
            uint32 ss = (uint32)(k == 0 ? s.x : k == 1 ? s.y : k == 2 ? s.z : s.w);
            uint32 b = dd >> BUCKET_SHIFT, dl = dd & (BUCKET_NODES - 1);
            uint32 slot = atomicAdd(&pos[b], 1u);
            if (slot < T2_CAP) sorted[(size_t)b * T2_CAP + slot] = (dl << 20) | ss;
        }
    }
}

__global__ __launch_bounds__(1024)
void bucket_reduce(const uint32* __restrict__ sorted,
                   const uint32* __restrict__ gpos,
                   const float* __restrict__ x,
                   const int* __restrict__ batch,
                   float* __restrict__ sums,
                   float* __restrict__ counts) {
    __shared__ float acc[BUCKET_NODES];
    const int b = blockIdx.x;
    const int tid = threadIdx.x;
    for (int n = tid; n < BUCKET_NODES; n += 1024) acc[n] = 0.0f;
    __syncthreads();
    uint32 cnt = gpos[b];
    if (cnt > T2_CAP) cnt = T2_CAP;
    const uint32* reg = sorted + (size_t)b * T2_CAP;
    const vuint4* r4 = (const vuint4*)reg;
    const uint32 nvec = cnt / 4;
    for (uint32 i = tid; i < nvec; i += 1024) {
        vuint4 v = r4[i];
        atomicAdd(&acc[v.x >> 20], x[v.x & 0xFFFFFu]);
        atomicAdd(&acc[v.y >> 20], x[v.y & 0xFFFFFu]);
        atomicAdd(&acc[v.z >> 20], x[v.z & 0xFFFFFu]);
        atomicAdd(&acc[v.w >> 20], x[v.w & 0xFFFFFu]);
    }
    for (uint32 i = nvec * 4 + tid; i < cnt; i += 1024) {
        uint32 v = reg[i];
        atomicAdd(&acc[v >> 20], x[v & 0xFFFFFu]);
    }
    __syncthreads();
    const int node0 = b << BUCKET_SHIFT;
    for (int n = tid; n < BUCKET_NODES; n += 1024) {
        int i = node0 + n;
        float h = 0.0f;
        int g = -1;
        if (i < N_NODES) {
            h = fmaxf(acc[n], 0.0f);
            g = batch[i];
        }
        int g0 = __shfl(g, 0);
        if (__all(g == g0)) {
            #pragma unroll
            for (int off = 32; off > 0; off >>= 1)
                h += __shfl_down(h, off);
            if ((tid & 63) == 0 && g0 >= 0) {
                atomicAdd(&sums[g0], h);
                atomicAdd(&counts[g0], 64.0f);
            }
        } else if (g >= 0) {
            atomicAdd(&sums[g], h);
            atomicAdd(&counts[g], 1.0f);
        }
    }
}

// Tier 3 fallback: device-atomic scatter (slow but correct)
__global__ void scatter_edges_dev(const vint4* __restrict__ src4,
                                  const vint4* __restrict__ dst4,
                                  const float* __restrict__ x,
                                  float* __restrict__ agg) {
    int t = blockIdx.x * blockDim.x + threadIdx.x;
    if (t < N_EDGES / 4) {
        vint4 s = __builtin_nontemporal_load(&src4[t]);
        vint4 d = __builtin_nontemporal_load(&dst4[t]);
        atomicAdd(&agg[d.x], x[s.x]);
        atomicAdd(&agg[d.y], x[s.y]);
        atomicAdd(&agg[d.z], x[s.z]);
        atomicAdd(&agg[d.w], x[s.w]);
    }
}

__global__ void pool_nodes_kernel(const float* __restrict__ agg,
                                  const int* __restrict__ batch,
                                  float* __restrict__ sums,
                                  float* __restrict__ counts) {
    int i = blockIdx.x * blockDim.x + threadIdx.x;
    float h = 0.0f;
    int g = -1;
    if (i < N_NODES) {
        h = fmaxf(agg[i], 0.0f);
        g = batch[i];
    }
    int g0 = __shfl(g, 0);
    if (__all(g == g0)) {
        #pragma unroll
        for (int off = 32; off > 0; off >>= 1)
            h += __shfl_down(h, off);
        if ((threadIdx.x & 63) == 0 && g0 >= 0) {
            atomicAdd(&sums[g0], h);
            atomicAdd(&counts[g0], 64.0f);
        }
    } else if (g >= 0) {
        atomicAdd(&sums[g], h);
        atomicAdd(&counts[g], 1.0f);
    }
}

extern "C" void kernel_launch(void* const* d_in, const int* in_sizes, int n_in,
                              void* d_out, int out_size, void* d_ws, size_t ws_size,
                              hipStream_t stream) {
    const float* x     = (const float*)d_in[0];
    const float* W     = (const float*)d_in[1];
    const float* b     = (const float*)d_in[2];
    const int*   edge  = (const int*)d_in[3];   // [2, N_EDGES] int32
    const int*   batch = (const int*)d_in[4];   // [N_NODES] int32, sorted
    float* out = (float*)d_out;

    const int* src = edge;             // row 0
    const int* dst = edge + N_EDGES;   // row 1

    const size_t ncells     = (size_t)NBUCKETS * T1_NCHUNK;           // 125440
    const size_t slab_elems = ncells * SLAB_CAP;                      // 46,161,920
    const size_t nagg       = (size_t)NBUCKETS * BUCKET_NODES;        // 1,003,520
    const size_t need0 = (slab_elems + 2 * ncells + nagg + 2 * NUM_GRAPHS) * 4;
    const size_t need1 = (slab_elems + 2 * ncells + 2 * NUM_GRAPHS) * 4;
    const size_t t2_elems = (size_t)NBUCKETS * T2_CAP;                // 33,367,040
    const size_t need2 = (t2_elems + 256 + 2 * NUM_GRAPHS) * 4;

    if (ws_size >= need0) {
        // --- Tier 0: src-affine split reduce + separate pool pass ---
        uint32* slab   = (uint32*)d_ws;
        uint32* fcnt_g = slab + slab_elems;
        uint32* ecnt_g = fcnt_g + ncells;
        float*  agg    = (float*)(ecnt_g + ncells);
        float*  sums   = agg + nagg;
        float*  counts = sums + NUM_GRAPHS;
        (void)hipMemsetAsync(agg, 0, (nagg + 2 * NUM_GRAPHS) * 4, stream);

        slab_scatter<<<T1_NCHUNK, T1_BLOCK, 0, stream>>>(src, dst, slab, fcnt_g, ecnt_g);
        slab_reduce2<<<NBUCKETS * RSPLIT * SRC_SPLIT, 1024, 0, stream>>>(
            slab, fcnt_g, ecnt_g, x, agg);
        pool_nodes_kernel<<<(N_NODES + 255) / 256, 256, 0, stream>>>(agg, batch, sums, counts);
        finalize_kernel<<<(NUM_GRAPHS + 255) / 256, 256, 0, stream>>>(sums, counts, W, b, out);
    } else if (ws_size >= need1) {
        uint32* slab   = (uint32*)d_ws;
        uint32* fcnt_g = slab + slab_elems;
        uint32* ecnt_g = fcnt_g + ncells;
        float*  sums   = (float*)(ecnt_g + ncells);
        float*  counts = sums + NUM_GRAPHS;
        (void)hipMemsetAsync(sums, 0, 2 * NUM_GRAPHS * 4, stream);

        slab_scatter<<<T1_NCHUNK, T1_BLOCK, 0, stream>>>(src, dst, slab, fcnt_g, ecnt_g);
        slab_reduce<<<NBUCKETS, 1024, 0, stream>>>(slab, fcnt_g, ecnt_g, x, batch, sums, counts);
        finalize_kernel<<<(NUM_GRAPHS + 255) / 256, 256, 0, stream>>>(sums, counts, W, b, out);
    } else if (ws_size >= need2) {
        uint32* sorted = (uint32*)d_ws;
        uint32* gpos   = sorted + t2_elems;
        float*  sums   = (float*)(gpos + 256);
        float*  counts = sums + NUM_GRAPHS;
        (void)hipMemsetAsync(gpos, 0, (256 + 2 * NUM_GRAPHS) * 4, stream);

        bucket_scatter<<<T2_NCHUNK, 1024, 0, stream>>>(src, dst, sorted, gpos);
        bucket_reduce<<<NBUCKETS, 1024, 0, stream>>>(sorted, gpos, x, batch, sums, counts);
        finalize_kernel<<<(NUM_GRAPHS + 255) / 256, 256, 0, stream>>>(sums, counts, W, b, out);
    } else {
        float* agg    = (float*)d_ws;
        float* sums   = agg + N_NODES;
        float* counts = sums + NUM_GRAPHS;
        (void)hipMemsetAsync(d_ws, 0, ((size_t)N_NODES + 2 * NUM_GRAPHS) * 4, stream);

        int nthreads = N_EDGES / 4;
        scatter_edges_dev<<<(nthreads + 255) / 256, 256, 0, stream>>>(
            (const vint4*)src, (const vint4*)dst, x, agg);
        pool_nodes_kernel<<<(N_NODES + 255) / 256, 256, 0, stream>>>(agg, batch, sums, counts);
        finalize_kernel<<<(NUM_GRAPHS + 255) / 256, 256, 0, stream>>>(sums, counts, W, b, out);
    }
}

// Round 5
// 659.920 us; speedup vs baseline: 1.0494x; 1.0494x over previous
//
#include <hip/hip_runtime.h>

#define N_NODES    1000000
#define N_EDGES    32000000
#define NUM_GRAPHS 1024

typedef int          vint4  __attribute__((ext_vector_type(4)));
typedef unsigned int uint32;
typedef unsigned int vuint4 __attribute__((ext_vector_type(4)));

#define BUCKET_SHIFT 12
#define BUCKET_NODES (1 << BUCKET_SHIFT)          // 4096 nodes/bucket
#define NBUCKETS     245                          // ceil(1e6 / 4096)

// ---- Tier 1: slab + LDS-staged line flush (r1-proven layout) ---------------
#define T1_NCHUNK   512
#define T1_BLOCK    512
#define T1_EDGES_PER_CHUNK (N_EDGES / T1_NCHUNK)  // 62500
#define T1_QUADS    (T1_EDGES_PER_CHUNK / 4)      // 15625
#define T1_QPR      (2 * T1_BLOCK)                // quads per round (2/thread)
#define T1_ROUNDS   ((T1_QUADS + T1_QPR - 1) / T1_QPR)   // 16
#define SCAP        64                            // LDS staging slots per bucket
#define SLAB_CAP    368                           // per-cell slots: mean 256 + 7 sigma, %16==0

// reduce: RSPLIT WGs per bucket (r1-proven: grid 980, ~80% occupancy)
#define RSPLIT        4
#define CELLS_PER_WG  (T1_NCHUNK / RSPLIT)        // 128

// ---- Tier 2 (known-good fallback path) --------------------------------------
#define T2_CAP      136192
#define T2_NCHUNK   512
#define T2_EPC      (N_EDGES / T2_NCHUNK)

// ============================================================================
// Tier 1 scatter: rounds of 4096 edges (2 quads = 8 edges per thread):
//   phase A: claim staging slot via LDS atomic; idx < SCAP -> stage in LDS,
//            else (rare) guarded direct store to slab tail.
//   phase B: flush complete 16-entry (64B) lines coalesced, compact remainder.
// 2-quad unroll = 8 independent LDS atomic->store chains per thread per round
// (MLP on the LDS latency chains); rounds 31 -> 16 halves barrier count.
// ============================================================================
__global__ __launch_bounds__(T1_BLOCK)
void slab_scatter(const int* __restrict__ src,
                  const int* __restrict__ dst,
                  uint32* __restrict__ slab,
                  uint32* __restrict__ fcnt_g,
                  uint32* __restrict__ ecnt_g) {
    __shared__ uint32 stage[NBUCKETS][SCAP];  // 62.7 KB
    __shared__ uint32 rpos[NBUCKETS];         // claims this round
    __shared__ uint32 ecnt[NBUCKETS];         // tail (overflow) count
    __shared__ uint32 flushed[NBUCKETS];      // front entries already in slab
    __shared__ uint32 carry[NBUCKETS];        // staged entries carried across rounds

    const int tid = threadIdx.x;
    const int w   = blockIdx.x;
    const vint4* d4 = (const vint4*)(dst + (size_t)w * T1_EDGES_PER_CHUNK);
    const vint4* s4 = (const vint4*)(src + (size_t)w * T1_EDGES_PER_CHUNK);

    for (int b = tid; b < NBUCKETS; b += T1_BLOCK) {
        rpos[b] = 0; ecnt[b] = 0; flushed[b] = 0; carry[b] = 0;
    }
    __syncthreads();

    const int grp    = tid >> 4;    // 32 groups of 16 lanes
    const int lane16 = tid & 15;

    for (int r = 0; r < T1_ROUNDS; ++r) {
        const int q0 = r * T1_QPR + tid;
        const int q1 = q0 + T1_BLOCK;
        const bool ok0 = q0 < T1_QUADS;
        const bool ok1 = q1 < T1_QUADS;
        vint4 d0, s0, d1, s1;
        if (ok0) { d0 = __builtin_nontemporal_load(&d4[q0]);
                   s0 = __builtin_nontemporal_load(&s4[q0]); }
        if (ok1) { d1 = __builtin_nontemporal_load(&d4[q1]);
                   s1 = __builtin_nontemporal_load(&s4[q1]); }

#define SCAT4(dd4, ss4)                                                        \
        {                                                                      \
            _Pragma("unroll")                                                  \
            for (int k = 0; k < 4; ++k) {                                      \
                uint32 dd = (uint32)(k == 0 ? dd4.x : k == 1 ? dd4.y :         \
                                     k == 2 ? dd4.z : dd4.w);                  \
                uint32 ss = (uint32)(k == 0 ? ss4.x : k == 1 ? ss4.y :         \
                                     k == 2 ? ss4.z : ss4.w);                  \
                uint32 b  = dd >> BUCKET_SHIFT;                                \
                uint32 v  = ((dd & (BUCKET_NODES - 1)) << 20) | ss;            \
                uint32 c  = carry[b] + atomicAdd(&rpos[b], 1u);                \
                if (c < SCAP) {                                                \
                    stage[b][c] = v;                                           \
                } else {                                                       \
                    uint32 e = atomicAdd(&ecnt[b], 1u);                        \
                    if (e < SLAB_CAP)  /* safety guard, ~never taken */        \
                        __builtin_nontemporal_store(v,                         \
                            &slab[((size_t)b * T1_NCHUNK + w) * SLAB_CAP       \
                                  + (SLAB_CAP - 1 - e)]);                      \
                }                                                              \
            }                                                                  \
        }
        if (ok0) SCAT4(d0, s0)
        if (ok1) SCAT4(d1, s1)
#undef SCAT4
        __syncthreads();
        // phase B: flush complete lines; 16-lane group owns buckets grp, grp+32, ...
        for (int b = grp; b < NBUCKETS; b += 32) {
            uint32 tot = carry[b] + rpos[b];
            if (tot > SCAP) tot = SCAP;
            uint32 lines = tot >> 4;
            uint32 rem   = tot & 15u;
            uint32 fl    = flushed[b];
            uint32 maxl  = (SLAB_CAP > fl) ? ((SLAB_CAP - fl) >> 4) : 0u;  // guard
            if (lines > maxl) lines = maxl;
            uint32* dp = slab + ((size_t)b * T1_NCHUNK + w) * SLAB_CAP + fl;
            for (uint32 l = 0; l < lines; ++l)
                __builtin_nontemporal_store(stage[b][l * 16 + lane16],
                                            &dp[l * 16 + lane16]);   // 64B coalesced
            if (lines) {
                uint32 mv = 0;
                if (lane16 < rem) mv = stage[b][lines * 16 + lane16];
                if (lane16 < rem) stage[b][lane16] = mv;             // compact remainder
            }
            if (lane16 == 0) {
                flushed[b] = fl + lines * 16;
                carry[b]   = rem;
                rpos[b]    = 0;
            }
        }
        __syncthreads();
    }
    // epilogue: flush partial remainder, publish per-cell counts
    for (int b = grp; b < NBUCKETS; b += 32) {
        uint32 rem = carry[b];
        uint32 fl  = flushed[b];
        uint32* dp = slab + ((size_t)b * T1_NCHUNK + w) * SLAB_CAP + fl;
        if (lane16 < rem && fl + lane16 < SLAB_CAP)
            __builtin_nontemporal_store(stage[b][lane16], &dp[lane16]);
        if (lane16 == 0) {
            uint32 fc = fl + rem;
            fcnt_g[(size_t)b * T1_NCHUNK + w] = fc > SLAB_CAP ? SLAB_CAP : fc;
            ecnt_g[(size_t)b * T1_NCHUNK + w] = ecnt[b];
        }
    }
}

// ============================================================================
// Tier 1 reduce (r1 structure + 4-cell MLP pipeline): grid = 980 (2 WGs/CU).
// Per wave inner iteration: 4 independent slab quad-loads -> 16 independent
// x-gathers batched into registers -> 16 LDS atomics. In-flight gather lines
// per wave go 4 -> 16, attacking the serial slab->gather latency chain that
// the counters show (VALUBusy 5%, HBM 8%, occupancy 80% => latency-bound).
// ============================================================================
__global__ __launch_bounds__(1024)
void slab_reduce2(const uint32* __restrict__ slab,
                  const uint32* __restrict__ fcnt_g,
                  const uint32* __restrict__ ecnt_g,
                  const float* __restrict__ x,
                  float* __restrict__ agg) {
    __shared__ float  acc[BUCKET_NODES];
    __shared__ uint32 fc_s[CELLS_PER_WG];
    __shared__ uint32 ec_s[CELLS_PER_WG];

    const int b    = blockIdx.x / RSPLIT;
    const int part = blockIdx.x % RSPLIT;
    const int tid  = threadIdx.x;

    for (int n = tid; n < BUCKET_NODES; n += 1024) acc[n] = 0.0f;
    if (tid < CELLS_PER_WG) {
        size_t cell = (size_t)b * T1_NCHUNK + (size_t)part * CELLS_PER_WG + tid;
        uint32 fc = fcnt_g[cell];
        uint32 ec = ecnt_g[cell];
        if (fc > SLAB_CAP) fc = SLAB_CAP;   // safety clamps
        if (ec > SLAB_CAP) ec = SLAB_CAP;
        fc_s[tid] = fc;
        ec_s[tid] = ec;
    }
    __syncthreads();

    const int wv = tid >> 6, lane = tid & 63;
    // 16 waves per WG; wave wv owns cells {wv + 16k}. Process 4 cells at once.
    for (int cp = wv; cp < CELLS_PER_WG; cp += 64) {
        const int cA = cp, cB = cp + 16, cC = cp + 32, cD = cp + 48;
        const uint32 fcA = fc_s[cA], fcB = fc_s[cB], fcC = fc_s[cC], fcD = fc_s[cD];
        const uint32* baseA = slab + ((size_t)b * T1_NCHUNK + part * CELLS_PER_WG + cA) * SLAB_CAP;
        const uint32* baseB = slab + ((size_t)b * T1_NCHUNK + part * CELLS_PER_WG + cB) * SLAB_CAP;
        const uint32* baseC = slab + ((size_t)b * T1_NCHUNK + part * CELLS_PER_WG + cC) * SLAB_CAP;
        const uint32* baseD = slab + ((size_t)b * T1_NCHUNK + part * CELLS_PER_WG + cD) * SLAB_CAP;
        const uint32 nqA = fcA >> 2, nqB = fcB >> 2, nqC = fcC >> 2, nqD = fcD >> 2;
        uint32 nqM = nqA;
        if (nqB > nqM) nqM = nqB;
        if (nqC > nqM) nqM = nqC;
        if (nqD > nqM) nqM = nqD;

        for (uint32 i = lane; i < nqM; i += 64) {
            const bool aOK = i < nqA, bOK = i < nqB, cOK = i < nqC, dOK = i < nqD;
            vuint4 va, vb, vc, vd;
            if (aOK) va = __builtin_nontemporal_load(&((const vuint4*)baseA)[i]);
            if (bOK) vb = __builtin_nontemporal_load(&((const vuint4*)baseB)[i]);
            if (cOK) vc = __builtin_nontemporal_load(&((const vuint4*)baseC)[i]);
            if (dOK) vd = __builtin_nontemporal_load(&((const vuint4*)baseD)[i]);
            // batch the 16 gathers into registers (independent, all in flight)
            float xa0, xa1, xa2, xa3, xb0, xb1, xb2, xb3;
            float xc0, xc1, xc2, xc3, xd0, xd1, xd2, xd3;
            if (aOK) { xa0 = x[va.x & 0xFFFFFu]; xa1 = x[va.y & 0xFFFFFu];
                       xa2 = x[va.z & 0xFFFFFu]; xa3 = x[va.w & 0xFFFFFu]; }
            if (bOK) { xb0 = x[vb.x & 0xFFFFFu]; xb1 = x[vb.y & 0xFFFFFu];
                       xb2 = x[vb.z & 0xFFFFFu]; xb3 = x[vb.w & 0xFFFFFu]; }
            if (cOK) { xc0 = x[vc.x & 0xFFFFFu]; xc1 = x[vc.y & 0xFFFFFu];
                       xc2 = x[vc.z & 0xFFFFFu]; xc3 = x[vc.w & 0xFFFFFu]; }
            if (dOK) { xd0 = x[vd.x & 0xFFFFFu]; xd1 = x[vd.y & 0xFFFFFu];
                       xd2 = x[vd.z & 0xFFFFFu]; xd3 = x[vd.w & 0xFFFFFu]; }
            if (aOK) { atomicAdd(&acc[va.x >> 20], xa0); atomicAdd(&acc[va.y >> 20], xa1);
                       atomicAdd(&acc[va.z >> 20], xa2); atomicAdd(&acc[va.w >> 20], xa3); }
            if (bOK) { atomicAdd(&acc[vb.x >> 20], xb0); atomicAdd(&acc[vb.y >> 20], xb1);
                       atomicAdd(&acc[vb.z >> 20], xb2); atomicAdd(&acc[vb.w >> 20], xb3); }
            if (cOK) { atomicAdd(&acc[vc.x >> 20], xc0); atomicAdd(&acc[vc.y >> 20], xc1);
                       atomicAdd(&acc[vc.z >> 20], xc2); atomicAdd(&acc[vc.w >> 20], xc3); }
            if (dOK) { atomicAdd(&acc[vd.x >> 20], xd0); atomicAdd(&acc[vd.y >> 20], xd1);
                       atomicAdd(&acc[vd.z >> 20], xd2); atomicAdd(&acc[vd.w >> 20], xd3); }
        }
        // remainders (fc & 3) and tails, per cell (tiny)
#define REM(base, fc, ec)                                                      \
        {                                                                      \
            for (uint32 i = ((fc) & ~3u) + lane; i < (fc); i += 64) {          \
                uint32 v = __builtin_nontemporal_load(&(base)[i]);             \
                atomicAdd(&acc[v >> 20], x[v & 0xFFFFFu]);                     \
            }                                                                  \
            for (uint32 i = lane; i < (ec); i += 64) {                         \
                uint32 v = (base)[SLAB_CAP - 1 - i];                           \
                atomicAdd(&acc[v >> 20], x[v & 0xFFFFFu]);                     \
            }                                                                  \
        }
        REM(baseA, fcA, ec_s[cA])
        REM(baseB, fcB, ec_s[cB])
        REM(baseC, fcC, ec_s[cC])
        REM(baseD, fcD, ec_s[cD])
#undef REM
    }
    __syncthreads();

    // coalesced device-scope merge of this WG's partial sums
    const int node0 = b << BUCKET_SHIFT;
    for (int n = tid; n < BUCKET_NODES; n += 1024) {
        float v = acc[n];
        if (v != 0.0f) atomicAdd(&agg[node0 + n], v);
    }
}

// Stage 3: out[g] = (sums[g] / max(counts[g],1)) * W + b
__global__ void finalize_kernel(const float* __restrict__ sums,
                                const float* __restrict__ counts,
                                const float* __restrict__ W,
                                const float* __restrict__ b,
                                float* __restrict__ out) {
    int g = blockIdx.x * blockDim.x + threadIdx.x;
    if (g < NUM_GRAPHS) {
        float pooled = sums[g] / fmaxf(counts[g], 1.0f);
        out[g] = pooled * W[0] + b[0];
    }
}

// ============================================================================
// Tier 2: known-good fallback (atomic block reservation + random stores)
// ============================================================================
__global__ __launch_bounds__(1024)
void bucket_scatter(const int* __restrict__ src,
                    const int* __restrict__ dst,
                    uint32* __restrict__ sorted,
                    uint32* __restrict__ gpos) {
    __shared__ uint32 hist[NBUCKETS];
    __shared__ uint32 pos[NBUCKETS];
    const int tid = threadIdx.x;
    const size_t base = (size_t)blockIdx.x * T2_EPC;
    for (int b = tid; b < NBUCKETS; b += 1024) hist[b] = 0;
    __syncthreads();
    const vint4* d4 = (const vint4*)(dst + base);
    const vint4* s4 = (const vint4*)(src + base);
    const int nvec = T2_EPC / 4;
    for (int i = tid; i < nvec; i += 1024) {
        vint4 d = d4[i];
        atomicAdd(&hist[(uint32)d.x >> BUCKET_SHIFT], 1u);
        atomicAdd(&hist[(uint32)d.y >> BUCKET_SHIFT], 1u);
        atomicAdd(&hist[(uint32)d.z >> BUCKET_SHIFT], 1u);
        atomicAdd(&hist[(uint32)d.w >> BUCKET_SHIFT], 1u);
    }
    __syncthreads();
    for (int b = tid; b < NBUCKETS; b += 1024)
        pos[b] = atomicAdd(&gpos[b], hist[b]);
    __syncthreads();
    for (int i = tid; i < nvec; i += 1024) {
        vint4 d = d4[i];
        vint4 s = s4[i];
        #pragma unroll
        for (int k = 0; k < 4; ++k) {
            uint32 dd = (uint32)(k == 0 ? d.x : k == 1 ? d.y : k == 2 ? d.z : d.w);
            uint32 ss = (uint32)(k == 0 ? s.x : k == 1 ? s.y : k == 2 ? s.z : s.w);
            uint32 b = dd >> BUCKET_SHIFT, dl = dd & (BUCKET_NODES - 1);
            uint32 slot = atomicAdd(&pos[b], 1u);
            if (slot < T2_CAP) sorted[(size_t)b * T2_CAP + slot] = (dl << 20) | ss;
        }
    }
}

__global__ __launch_bounds__(1024)
void bucket_reduce(const uint32* __restrict__ sorted,
                   const uint32* __restrict__ gpos,
                   const float* __restrict__ x,
                   const int* __restrict__ batch,
                   float* __restrict__ sums,
                   float* __restrict__ counts) {
    __shared__ float acc[BUCKET_NODES];
    const int b = blockIdx.x;
    const int tid = threadIdx.x;
    for (int n = tid; n < BUCKET_NODES; n += 1024) acc[n] = 0.0f;
    __syncthreads();
    uint32 cnt = gpos[b];
    if (cnt > T2_CAP) cnt = T2_CAP;
    const uint32* reg = sorted + (size_t)b * T2_CAP;
    const vuint4* r4 = (const vuint4*)reg;
    const uint32 nvec = cnt / 4;
    for (uint32 i = tid; i < nvec; i += 1024) {
        vuint4 v = r4[i];
        atomicAdd(&acc[v.x >> 20], x[v.x & 0xFFFFFu]);
        atomicAdd(&acc[v.y >> 20], x[v.y & 0xFFFFFu]);
        atomicAdd(&acc[v.z >> 20], x[v.z & 0xFFFFFu]);
        atomicAdd(&acc[v.w >> 20], x[v.w & 0xFFFFFu]);
    }
    for (uint32 i = nvec * 4 + tid; i < cnt; i += 1024) {
        uint32 v = reg[i];
        atomicAdd(&acc[v >> 20], x[v & 0xFFFFFu]);
    }
    __syncthreads();
    const int node0 = b << BUCKET_SHIFT;
    for (int n = tid; n < BUCKET_NODES; n += 1024) {
        int i = node0 + n;
        float h = 0.0f;
        int g = -1;
        if (i < N_NODES) {
            h = fmaxf(acc[n], 0.0f);
            g = batch[i];
        }
        int g0 = __shfl(g, 0);
        if (__all(g == g0)) {
            #pragma unroll
            for (int off = 32; off > 0; off >>= 1)
                h += __shfl_down(h, off);
            if ((tid & 63) == 0 && g0 >= 0) {
                atomicAdd(&sums[g0], h);
                atomicAdd(&counts[g0], 64.0f);
            }
        } else if (g >= 0) {
            atomicAdd(&sums[g], h);
            atomicAdd(&counts[g], 1.0f);
        }
    }
}

// Tier 3 fallback: device-atomic scatter (slow but correct)
__global__ void scatter_edges_dev(const vint4* __restrict__ src4,
                                  const vint4* __restrict__ dst4,
                                  const float* __restrict__ x,
                                  float* __restrict__ agg) {
    int t = blockIdx.x * blockDim.x + threadIdx.x;
    if (t < N_EDGES / 4) {
        vint4 s = __builtin_nontemporal_load(&src4[t]);
        vint4 d = __builtin_nontemporal_load(&dst4[t]);
        atomicAdd(&agg[d.x], x[s.x]);
        atomicAdd(&agg[d.y], x[s.y]);
        atomicAdd(&agg[d.z], x[s.z]);
        atomicAdd(&agg[d.w], x[s.w]);
    }
}

__global__ void pool_nodes_kernel(const float* __restrict__ agg,
                                  const int* __restrict__ batch,
                                  float* __restrict__ sums,
                                  float* __restrict__ counts) {
    int i = blockIdx.x * blockDim.x + threadIdx.x;
    float h = 0.0f;
    int g = -1;
    if (i < N_NODES) {
        h = fmaxf(agg[i], 0.0f);
        g = batch[i];
    }
    int g0 = __shfl(g, 0);
    if (__all(g == g0)) {
        #pragma unroll
        for (int off = 32; off > 0; off >>= 1)
            h += __shfl_down(h, off);
        if ((threadIdx.x & 63) == 0 && g0 >= 0) {
            atomicAdd(&sums[g0], h);
            atomicAdd(&counts[g0], 64.0f);
        }
    } else if (g >= 0) {
        atomicAdd(&sums[g], h);
        atomicAdd(&counts[g], 1.0f);
    }
}

extern "C" void kernel_launch(void* const* d_in, const int* in_sizes, int n_in,
                              void* d_out, int out_size, void* d_ws, size_t ws_size,
                              hipStream_t stream) {
    const float* x     = (const float*)d_in[0];
    const float* W     = (const float*)d_in[1];
    const float* b     = (const float*)d_in[2];
    const int*   edge  = (const int*)d_in[3];   // [2, N_EDGES] int32
    const int*   batch = (const int*)d_in[4];   // [N_NODES] int32, sorted
    float* out = (float*)d_out;

    const int* src = edge;             // row 0
    const int* dst = edge + N_EDGES;   // row 1

    const size_t ncells     = (size_t)NBUCKETS * T1_NCHUNK;           // 125440
    const size_t slab_elems = ncells * SLAB_CAP;                      // 46,161,920
    const size_t nagg       = (size_t)NBUCKETS * BUCKET_NODES;        // 1,003,520
    const size_t need0 = (slab_elems + 2 * ncells + nagg + 2 * NUM_GRAPHS) * 4;
    const size_t t2_elems = (size_t)NBUCKETS * T2_CAP;                // 33,367,040
    const size_t need2 = (t2_elems + 256 + 2 * NUM_GRAPHS) * 4;

    if (ws_size >= need0) {
        // --- Tier 0: MLP-unrolled scatter+reduce (r1-proven structure) ---
        uint32* slab   = (uint32*)d_ws;
        uint32* fcnt_g = slab + slab_elems;
        uint32* ecnt_g = fcnt_g + ncells;
        float*  agg    = (float*)(ecnt_g + ncells);
        float*  sums   = agg + nagg;
        float*  counts = sums + NUM_GRAPHS;
        (void)hipMemsetAsync(agg, 0, (nagg + 2 * NUM_GRAPHS) * 4, stream);

        slab_scatter<<<T1_NCHUNK, T1_BLOCK, 0, stream>>>(src, dst, slab, fcnt_g, ecnt_g);
        slab_reduce2<<<NBUCKETS * RSPLIT, 1024, 0, stream>>>(slab, fcnt_g, ecnt_g, x, agg);
        pool_nodes_kernel<<<(N_NODES + 255) / 256, 256, 0, stream>>>(agg, batch, sums, counts);
        finalize_kernel<<<(NUM_GRAPHS + 255) / 256, 256, 0, stream>>>(sums, counts, W, b, out);
    } else if (ws_size >= need2) {
        uint32* sorted = (uint32*)d_ws;
        uint32* gpos   = sorted + t2_elems;
        float*  sums   = (float*)(gpos + 256);
        float*  counts = sums + NUM_GRAPHS;
        (void)hipMemsetAsync(gpos, 0, (256 + 2 * NUM_GRAPHS) * 4, stream);

        bucket_scatter<<<T2_NCHUNK, 1024, 0, stream>>>(src, dst, sorted, gpos);
        bucket_reduce<<<NBUCKETS, 1024, 0, stream>>>(sorted, gpos, x, batch, sums, counts);
        finalize_kernel<<<(NUM_GRAPHS + 255) / 256, 256, 0, stream>>>(sums, counts, W, b, out);
    } else {
        float* agg    = (float*)d_ws;
        float* sums   = agg + N_NODES;
        float* counts = sums + NUM_GRAPHS;
        (void)hipMemsetAsync(d_ws, 0, ((size_t)N_NODES + 2 * NUM_GRAPHS) * 4, stream);

        int nthreads = N_EDGES / 4;
        scatter_edges_dev<<<(nthreads + 255) / 256, 256, 0, stream>>>(
            (const vint4*)src, (const vint4*)dst, x, agg);
        pool_nodes_kernel<<<(N_NODES + 255) / 256, 256, 0, stream>>>(agg, batch, sums, counts);
        finalize_kernel<<<(NUM_GRAPHS + 255) / 256, 256, 0, stream>>>(sums, counts, W, b, out);
    }
}

// Round 6
// 644.086 us; speedup vs baseline: 1.0752x; 1.0246x over previous
//
#include <hip/hip_runtime.h>

#define N_NODES    1000000
#define N_EDGES    32000000
#define NUM_GRAPHS 1024

typedef int          vint4  __attribute__((ext_vector_type(4)));
typedef unsigned int uint32;
typedef unsigned int vuint4 __attribute__((ext_vector_type(4)));

#define BUCKET_SHIFT 12
#define BUCKET_NODES (1 << BUCKET_SHIFT)          // 4096 nodes/bucket
#define NBUCKETS     245                          // ceil(1e6 / 4096)

// ---- Tier 1: slab + LDS-staged line flush (r1/r5-proven layout) ------------
#define T1_NCHUNK   512
#define T1_BLOCK    512
#define T1_EDGES_PER_CHUNK (N_EDGES / T1_NCHUNK)  // 62500
#define T1_QUADS    (T1_EDGES_PER_CHUNK / 4)      // 15625
#define T1_QPR      (2 * T1_BLOCK)                // quads per round (2/thread)
#define T1_ROUNDS   ((T1_QUADS + T1_QPR - 1) / T1_QPR)   // 16
#define SCAP        64                            // LDS staging slots per bucket
#define SLAB_CAP    368                           // per-cell slots: mean 256 + 7 sigma, %16==0

// reduce: RSPLIT WGs per bucket (proven: grid 980, ~80% occupancy)
#define RSPLIT        4
#define CELLS_PER_WG  (T1_NCHUNK / RSPLIT)        // 128

// ---- Tier 2 (known-good fallback path) --------------------------------------
#define T2_CAP      136192
#define T2_NCHUNK   512
#define T2_EPC      (N_EDGES / T2_NCHUNK)

// global_load_lds: per-lane GLOBAL src address, LDS dest = uniform base + lane*4.
// This is the DMA fill path (bypasses L1/VGPR return) — the whole experiment.
#define GLDS(gp, lp) __builtin_amdgcn_global_load_lds(                         \
    (const __attribute__((address_space(1))) void*)(gp),                       \
    (__attribute__((address_space(3))) void*)(lp), 4, 0, 0)

// ============================================================================
// Tier 1 scatter (unchanged from r5, harness-proven): rounds of 4096 edges
// (2 quads/thread): LDS-claim staging + 64B coalesced line flush.
// ============================================================================
__global__ __launch_bounds__(T1_BLOCK)
void slab_scatter(const int* __restrict__ src,
                  const int* __restrict__ dst,
                  uint32* __restrict__ slab,
                  uint32* __restrict__ fcnt_g,
                  uint32* __restrict__ ecnt_g) {
    __shared__ uint32 stage[NBUCKETS][SCAP];  // 62.7 KB
    __shared__ uint32 rpos[NBUCKETS];         // claims this round
    __shared__ uint32 ecnt[NBUCKETS];         // tail (overflow) count
    __shared__ uint32 flushed[NBUCKETS];      // front entries already in slab
    __shared__ uint32 carry[NBUCKETS];        // staged entries carried across rounds

    const int tid = threadIdx.x;
    const int w   = blockIdx.x;
    const vint4* d4 = (const vint4*)(dst + (size_t)w * T1_EDGES_PER_CHUNK);
    const vint4* s4 = (const vint4*)(src + (size_t)w * T1_EDGES_PER_CHUNK);

    for (int b = tid; b < NBUCKETS; b += T1_BLOCK) {
        rpos[b] = 0; ecnt[b] = 0; flushed[b] = 0; carry[b] = 0;
    }
    __syncthreads();

    const int grp    = tid >> 4;    // 32 groups of 16 lanes
    const int lane16 = tid & 15;

    for (int r = 0; r < T1_ROUNDS; ++r) {
        const int q0 = r * T1_QPR + tid;
        const int q1 = q0 + T1_BLOCK;
        const bool ok0 = q0 < T1_QUADS;
        const bool ok1 = q1 < T1_QUADS;
        vint4 d0, s0, d1, s1;
        if (ok0) { d0 = __builtin_nontemporal_load(&d4[q0]);
                   s0 = __builtin_nontemporal_load(&s4[q0]); }
        if (ok1) { d1 = __builtin_nontemporal_load(&d4[q1]);
                   s1 = __builtin_nontemporal_load(&s4[q1]); }

#define SCAT4(dd4, ss4)                                                        \
        {                                                                      \
            _Pragma("unroll")                                                  \
            for (int k = 0; k < 4; ++k) {                                      \
                uint32 dd = (uint32)(k == 0 ? dd4.x : k == 1 ? dd4.y :         \
                                     k == 2 ? dd4.z : dd4.w);                  \
                uint32 ss = (uint32)(k == 0 ? ss4.x : k == 1 ? ss4.y :         \
                                     k == 2 ? ss4.z : ss4.w);                  \
                uint32 b  = dd >> BUCKET_SHIFT;                                \
                uint32 v  = ((dd & (BUCKET_NODES - 1)) << 20) | ss;            \
                uint32 c  = carry[b] + atomicAdd(&rpos[b], 1u);                \
                if (c < SCAP) {                                                \
                    stage[b][c] = v;                                           \
                } else {                                                       \
                    uint32 e = atomicAdd(&ecnt[b], 1u);                        \
                    if (e < SLAB_CAP)  /* safety guard, ~never taken */        \
                        __builtin_nontemporal_store(v,                         \
                            &slab[((size_t)b * T1_NCHUNK + w) * SLAB_CAP       \
                                  + (SLAB_CAP - 1 - e)]);                      \
                }                                                              \
            }                                                                  \
        }
        if (ok0) SCAT4(d0, s0)
        if (ok1) SCAT4(d1, s1)
#undef SCAT4
        __syncthreads();
        // phase B: flush complete lines; 16-lane group owns buckets grp, grp+32, ...
        for (int b = grp; b < NBUCKETS; b += 32) {
            uint32 tot = carry[b] + rpos[b];
            if (tot > SCAP) tot = SCAP;
            uint32 lines = tot >> 4;
            uint32 rem   = tot & 15u;
            uint32 fl    = flushed[b];
            uint32 maxl  = (SLAB_CAP > fl) ? ((SLAB_CAP - fl) >> 4) : 0u;  // guard
            if (lines > maxl) lines = maxl;
            uint32* dp = slab + ((size_t)b * T1_NCHUNK + w) * SLAB_CAP + fl;
            for (uint32 l = 0; l < lines; ++l)
                __builtin_nontemporal_store(stage[b][l * 16 + lane16],
                                            &dp[l * 16 + lane16]);   // 64B coalesced
            if (lines) {
                uint32 mv = 0;
                if (lane16 < rem) mv = stage[b][lines * 16 + lane16];
                if (lane16 < rem) stage[b][lane16] = mv;             // compact remainder
            }
            if (lane16 == 0) {
                flushed[b] = fl + lines * 16;
                carry[b]   = rem;
                rpos[b]    = 0;
            }
        }
        __syncthreads();
    }
    // epilogue: flush partial remainder, publish per-cell counts
    for (int b = grp; b < NBUCKETS; b += 32) {
        uint32 rem = carry[b];
        uint32 fl  = flushed[b];
        uint32* dp = slab + ((size_t)b * T1_NCHUNK + w) * SLAB_CAP + fl;
        if (lane16 < rem && fl + lane16 < SLAB_CAP)
            __builtin_nontemporal_store(stage[b][lane16], &dp[lane16]);
        if (lane16 == 0) {
            uint32 fc = fl + rem;
            fcnt_g[(size_t)b * T1_NCHUNK + w] = fc > SLAB_CAP ? SLAB_CAP : fc;
            ecnt_g[(size_t)b * T1_NCHUNK + w] = ecnt[b];
        }
    }
}

// ============================================================================
// Tier 1 reduce v6: x-gathers via global_load_lds DMA (bypass L1 MSHR path).
// Per wave iteration: 2 cells, 2 NT slab quad-loads -> 8 global_load_lds
// (64 lanes x 4B each, per-lane global addr, uniform LDS base) -> vmcnt(0)
// -> stride-4B LDS readback (conflict-free) -> LDS atomicAdd.
// Theory: reduce was pinned at 4 cyc/edge = L1 MSHRs(~64) / L2 latency(~260cy)
// across occupancy 41->80% and ILP 4->16 (r0/r1/r5). DMA path is tracked by
// vmcnt, not L1 MSHRs.
// ============================================================================
__global__ __launch_bounds__(1024)
void slab_reduce2(const uint32* __restrict__ slab,
                  const uint32* __restrict__ fcnt_g,
                  const uint32* __restrict__ ecnt_g,
                  const float* __restrict__ x,
                  float* __restrict__ agg) {
    __shared__ float  acc[BUCKET_NODES];        // 16 KB
    __shared__ float  scr[16][8][64];           // 32 KB gather landing zone
    __shared__ uint32 fc_s[CELLS_PER_WG];
    __shared__ uint32 ec_s[CELLS_PER_WG];

    const int b    = blockIdx.x / RSPLIT;
    const int part = blockIdx.x % RSPLIT;
    const int tid  = threadIdx.x;

    for (int n = tid; n < BUCKET_NODES; n += 1024) acc[n] = 0.0f;
    if (tid < CELLS_PER_WG) {
        size_t cell = (size_t)b * T1_NCHUNK + (size_t)part * CELLS_PER_WG + tid;
        uint32 fc = fcnt_g[cell];
        uint32 ec = ecnt_g[cell];
        if (fc > SLAB_CAP) fc = SLAB_CAP;   // safety clamps
        if (ec > SLAB_CAP) ec = SLAB_CAP;
        fc_s[tid] = fc;
        ec_s[tid] = ec;
    }
    __syncthreads();

    const int wv = tid >> 6, lane = tid & 63;
    const size_t cbase = (size_t)b * T1_NCHUNK + (size_t)part * CELLS_PER_WG;

    // 16 waves; wave wv owns cell pairs (cp, cp+16) for cp in {wv, wv+32, ...}
    for (int cp = wv; cp < CELLS_PER_WG; cp += 32) {
        const int cA = cp, cB = cp + 16;
        const uint32 fcA = fc_s[cA], fcB = fc_s[cB];
        const uint32 ecA = ec_s[cA], ecB = ec_s[cB];
        const uint32* baseA = slab + (cbase + cA) * SLAB_CAP;
        const uint32* baseB = slab + (cbase + cB) * SLAB_CAP;
        const uint32 nqA = fcA >> 2, nqB = fcB >> 2;
        const uint32 nqM = nqA > nqB ? nqA : nqB;

        for (uint32 i = lane; i < nqM; i += 64) {
            const bool aOK = i < nqA, bOK = i < nqB;
            vuint4 va = {0, 0, 0, 0}, vb = {0, 0, 0, 0};
            if (aOK) va = __builtin_nontemporal_load(&((const vuint4*)baseA)[i]);
            if (bOK) vb = __builtin_nontemporal_load(&((const vuint4*)baseB)[i]);
            // 8 DMA gathers: per-lane global addr (clamped to x[0] when !ok),
            // LDS dest = uniform base + lane*4
            GLDS(x + (va.x & 0xFFFFFu), &scr[wv][0][0]);
            GLDS(x + (va.y & 0xFFFFFu), &scr[wv][1][0]);
            GLDS(x + (va.z & 0xFFFFFu), &scr[wv][2][0]);
            GLDS(x + (va.w & 0xFFFFFu), &scr[wv][3][0]);
            GLDS(x + (vb.x & 0xFFFFFu), &scr[wv][4][0]);
            GLDS(x + (vb.y & 0xFFFFFu), &scr[wv][5][0]);
            GLDS(x + (vb.z & 0xFFFFFu), &scr[wv][6][0]);
            GLDS(x + (vb.w & 0xFFFFFu), &scr[wv][7][0]);
            asm volatile("s_waitcnt vmcnt(0)" ::: "memory");
            __builtin_amdgcn_sched_barrier(0);
            float a0 = scr[wv][0][lane], a1 = scr[wv][1][lane];
            float a2 = scr[wv][2][lane], a3 = scr[wv][3][lane];
            float b0 = scr[wv][4][lane], b1 = scr[wv][5][lane];
            float b2 = scr[wv][6][lane], b3 = scr[wv][7][lane];
            if (aOK) { atomicAdd(&acc[va.x >> 20], a0); atomicAdd(&acc[va.y >> 20], a1);
                       atomicAdd(&acc[va.z >> 20], a2); atomicAdd(&acc[va.w >> 20], a3); }
            if (bOK) { atomicAdd(&acc[vb.x >> 20], b0); atomicAdd(&acc[vb.y >> 20], b1);
                       atomicAdd(&acc[vb.z >> 20], b2); atomicAdd(&acc[vb.w >> 20], b3); }
            __builtin_amdgcn_sched_barrier(0);   // pin next glds batch after reads
        }
        // remainders (fc & 3) and overflow tails, per cell (tiny, plain gathers)
#define REM(base, fc, ec)                                                      \
        {                                                                      \
            for (uint32 i = ((fc) & ~3u) + lane; i < (fc); i += 64) {          \
                uint32 v = __builtin_nontemporal_load(&(base)[i]);             \
                atomicAdd(&acc[v >> 20], x[v & 0xFFFFFu]);                     \
            }                                                                  \
            for (uint32 i = lane; i < (ec); i += 64) {                         \
                uint32 v = (base)[SLAB_CAP - 1 - i];                           \
                atomicAdd(&acc[v >> 20], x[v & 0xFFFFFu]);                     \
            }                                                                  \
        }
        REM(baseA, fcA, ecA)
        REM(baseB, fcB, ecB)
#undef REM
    }
    __syncthreads();

    // coalesced device-scope merge of this WG's partial sums
    const int node0 = b << BUCKET_SHIFT;
    for (int n = tid; n < BUCKET_NODES; n += 1024) {
        float v = acc[n];
        if (v != 0.0f) atomicAdd(&agg[node0 + n], v);
    }
}

// Stage 3: out[g] = (sums[g] / max(counts[g],1)) * W + b
__global__ void finalize_kernel(const float* __restrict__ sums,
                                const float* __restrict__ counts,
                                const float* __restrict__ W,
                                const float* __restrict__ b,
                                float* __restrict__ out) {
    int g = blockIdx.x * blockDim.x + threadIdx.x;
    if (g < NUM_GRAPHS) {
        float pooled = sums[g] / fmaxf(counts[g], 1.0f);
        out[g] = pooled * W[0] + b[0];
    }
}

// ============================================================================
// Tier 2: known-good fallback (atomic block reservation + random stores)
// ============================================================================
__global__ __launch_bounds__(1024)
void bucket_scatter(const int* __restrict__ src,
                    const int* __restrict__ dst,
                    uint32* __restrict__ sorted,
                    uint32* __restrict__ gpos) {
    __shared__ uint32 hist[NBUCKETS];
    __shared__ uint32 pos[NBUCKETS];
    const int tid = threadIdx.x;
    const size_t base = (size_t)blockIdx.x * T2_EPC;
    for (int b = tid; b < NBUCKETS; b += 1024) hist[b] = 0;
    __syncthreads();
    const vint4* d4 = (const vint4*)(dst + base);
    const vint4* s4 = (const vint4*)(src + base);
    const int nvec = T2_EPC / 4;
    for (int i = tid; i < nvec; i += 1024) {
        vint4 d = d4[i];
        atomicAdd(&hist[(uint32)d.x >> BUCKET_SHIFT], 1u);
        atomicAdd(&hist[(uint32)d.y >> BUCKET_SHIFT], 1u);
        atomicAdd(&hist[(uint32)d.z >> BUCKET_SHIFT], 1u);
        atomicAdd(&hist[(uint32)d.w >> BUCKET_SHIFT], 1u);
    }
    __syncthreads();
    for (int b = tid; b < NBUCKETS; b += 1024)
        pos[b] = atomicAdd(&gpos[b], hist[b]);
    __syncthreads();
    for (int i = tid; i < nvec; i += 1024) {
        vint4 d = d4[i];
        vint4 s = s4[i];
        #pragma unroll
        for (int k = 0; k < 4; ++k) {
            uint32 dd = (uint32)(k == 0 ? d.x : k == 1 ? d.y : k == 2 ? d.z : d.w);
            uint32 ss = (uint32)(k == 0 ? s.x : k == 1 ? s.y : k == 2 ? s.z : s.w);
            uint32 b = dd >> BUCKET_SHIFT, dl = dd & (BUCKET_NODES - 1);
            uint32 slot = atomicAdd(&pos[b], 1u);
            if (slot < T2_CAP) sorted[(size_t)b * T2_CAP + slot] = (dl << 20) | ss;
        }
    }
}

__global__ __launch_bounds__(1024)
void bucket_reduce(const uint32* __restrict__ sorted,
                   const uint32* __restrict__ gpos,
                   const float* __restrict__ x,
                   const int* __restrict__ batch,
                   float* __restrict__ sums,
                   float* __restrict__ counts) {
    __shared__ float acc[BUCKET_NODES];
    const int b = blockIdx.x;
    const int tid = threadIdx.x;
    for (int n = tid; n < BUCKET_NODES; n += 1024) acc[n] = 0.0f;
    __syncthreads();
    uint32 cnt = gpos[b];
    if (cnt > T2_CAP) cnt = T2_CAP;
    const uint32* reg = sorted + (size_t)b * T2_CAP;
    const vuint4* r4 = (const vuint4*)reg;
    const uint32 nvec = cnt / 4;
    for (uint32 i = tid; i < nvec; i += 1024) {
        vuint4 v = r4[i];
        atomicAdd(&acc[v.x >> 20], x[v.x & 0xFFFFFu]);
        atomicAdd(&acc[v.y >> 20], x[v.y & 0xFFFFFu]);
        atomicAdd(&acc[v.z >> 20], x[v.z & 0xFFFFFu]);
        atomicAdd(&acc[v.w >> 20], x[v.w & 0xFFFFFu]);
    }
    for (uint32 i = nvec * 4 + tid; i < cnt; i += 1024) {
        uint32 v = reg[i];
        atomicAdd(&acc[v >> 20], x[v & 0xFFFFFu]);
    }
    __syncthreads();
    const int node0 = b << BUCKET_SHIFT;
    for (int n = tid; n < BUCKET_NODES; n += 1024) {
        int i = node0 + n;
        float h = 0.0f;
        int g = -1;
        if (i < N_NODES) {
            h = fmaxf(acc[n], 0.0f);
            g = batch[i];
        }
        int g0 = __shfl(g, 0);
        if (__all(g == g0)) {
            #pragma unroll
            for (int off = 32; off > 0; off >>= 1)
                h += __shfl_down(h, off);
            if ((tid & 63) == 0 && g0 >= 0) {
                atomicAdd(&sums[g0], h);
                atomicAdd(&counts[g0], 64.0f);
            }
        } else if (g >= 0) {
            atomicAdd(&sums[g], h);
            atomicAdd(&counts[g], 1.0f);
        }
    }
}

// Tier 3 fallback: device-atomic scatter (slow but correct)
__global__ void scatter_edges_dev(const vint4* __restrict__ src4,
                                  const vint4* __restrict__ dst4,
                                  const float* __restrict__ x,
                                  float* __restrict__ agg) {
    int t = blockIdx.x * blockDim.x + threadIdx.x;
    if (t < N_EDGES / 4) {
        vint4 s = __builtin_nontemporal_load(&src4[t]);
        vint4 d = __builtin_nontemporal_load(&dst4[t]);
        atomicAdd(&agg[d.x], x[s.x]);
        atomicAdd(&agg[d.y], x[s.y]);
        atomicAdd(&agg[d.z], x[s.z]);
        atomicAdd(&agg[d.w], x[s.w]);
    }
}

__global__ void pool_nodes_kernel(const float* __restrict__ agg,
                                  const int* __restrict__ batch,
                                  float* __restrict__ sums,
                                  float* __restrict__ counts) {
    int i = blockIdx.x * blockDim.x + threadIdx.x;
    float h = 0.0f;
    int g = -1;
    if (i < N_NODES) {
        h = fmaxf(agg[i], 0.0f);
        g = batch[i];
    }
    int g0 = __shfl(g, 0);
    if (__all(g == g0)) {
        #pragma unroll
        for (int off = 32; off > 0; off >>= 1)
            h += __shfl_down(h, off);
        if ((threadIdx.x & 63) == 0 && g0 >= 0) {
            atomicAdd(&sums[g0], h);
            atomicAdd(&counts[g0], 64.0f);
        }
    } else if (g >= 0) {
        atomicAdd(&sums[g], h);
        atomicAdd(&counts[g], 1.0f);
    }
}

extern "C" void kernel_launch(void* const* d_in, const int* in_sizes, int n_in,
                              void* d_out, int out_size, void* d_ws, size_t ws_size,
                              hipStream_t stream) {
    const float* x     = (const float*)d_in[0];
    const float* W     = (const float*)d_in[1];
    const float* b     = (const float*)d_in[2];
    const int*   edge  = (const int*)d_in[3];   // [2, N_EDGES] int32
    const int*   batch = (const int*)d_in[4];   // [N_NODES] int32, sorted
    float* out = (float*)d_out;

    const int* src = edge;             // row 0
    const int* dst = edge + N_EDGES;   // row 1

    const size_t ncells     = (size_t)NBUCKETS * T1_NCHUNK;           // 125440
    const size_t slab_elems = ncells * SLAB_CAP;                      // 46,161,920
    const size_t nagg       = (size_t)NBUCKETS * BUCKET_NODES;        // 1,003,520
    const size_t need0 = (slab_elems + 2 * ncells + nagg + 2 * NUM_GRAPHS) * 4;
    const size_t t2_elems = (size_t)NBUCKETS * T2_CAP;                // 33,367,040
    const size_t need2 = (t2_elems + 256 + 2 * NUM_GRAPHS) * 4;

    if (ws_size >= need0) {
        // --- Tier 0: scatter + DMA-gather reduce (r5-proven structure) ---
        uint32* slab   = (uint32*)d_ws;
        uint32* fcnt_g = slab + slab_elems;
        uint32* ecnt_g = fcnt_g + ncells;
        float*  agg    = (float*)(ecnt_g + ncells);
        float*  sums   = agg + nagg;
        float*  counts = sums + NUM_GRAPHS;
        (void)hipMemsetAsync(agg, 0, (nagg + 2 * NUM_GRAPHS) * 4, stream);

        slab_scatter<<<T1_NCHUNK, T1_BLOCK, 0, stream>>>(src, dst, slab, fcnt_g, ecnt_g);
        slab_reduce2<<<NBUCKETS * RSPLIT, 1024, 0, stream>>>(slab, fcnt_g, ecnt_g, x, agg);
        pool_nodes_kernel<<<(N_NODES + 255) / 256, 256, 0, stream>>>(agg, batch, sums, counts);
        finalize_kernel<<<(NUM_GRAPHS + 255) / 256, 256, 0, stream>>>(sums, counts, W, b, out);
    } else if (ws_size >= need2) {
        uint32* sorted = (uint32*)d_ws;
        uint32* gpos   = sorted + t2_elems;
        float*  sums   = (float*)(gpos + 256);
        float*  counts = sums + NUM_GRAPHS;
        (void)hipMemsetAsync(gpos, 0, (256 + 2 * NUM_GRAPHS) * 4, stream);

        bucket_scatter<<<T2_NCHUNK, 1024, 0, stream>>>(src, dst, sorted, gpos);
        bucket_reduce<<<NBUCKETS, 1024, 0, stream>>>(sorted, gpos, x, batch, sums, counts);
        finalize_kernel<<<(NUM_GRAPHS + 255) / 256, 256, 0, stream>>>(sums, counts, W, b, out);
    } else {
        float* agg    = (float*)d_ws;
        float* sums   = agg + N_NODES;
        float* counts = sums + NUM_GRAPHS;
        (void)hipMemsetAsync(d_ws, 0, ((size_t)N_NODES + 2 * NUM_GRAPHS) * 4, stream);

        int nthreads = N_EDGES / 4;
        scatter_edges_dev<<<(nthreads + 255) / 256, 256, 0, stream>>>(
            (const vint4*)src, (const vint4*)dst, x, agg);
        pool_nodes_kernel<<<(N_NODES + 255) / 256, 256, 0, stream>>>(agg, batch, sums, counts);
        finalize_kernel<<<(NUM_GRAPHS + 255) / 256, 256, 0, stream>>>(sums, counts, W, b, out);
    }
}